// Round 4
// baseline (169.768 us; speedup 1.0000x reference)
//
#include <hip/hip_runtime.h>
#include <math.h>

#define N_PRED   8192
#define N_CLS    150
#define N_BATCH  16
#define T_DIM    (N_BATCH * N_CLS)          // 2400
#define NPIX     (N_BATCH * 1024 * 1024)    // 16777216
#define PIX_SHIFT 20                         // pixels per image = 2^20

#define STRIPE   16384                       // pixels per partition block
#define NBLK_A   (NPIX / STRIPE)             // 1024 (stripes never cross images)
#define NBUK     1024                        // p-buckets of 8 consecutive p
#define P_PER_BUK 8

#define KEYS_BYTES ((size_t)NPIX * 2)               // 33,554,432  (u16 keys)
#define DIR_BYTES  ((size_t)NBLK_A * NBUK * 4)      // 4,194,304
#define NT_BYTES   ((size_t)T_DIM * 4)              // 9,600
#define OUT_BYTES  ((size_t)N_PRED * N_CLS * 4)     // 4,915,200

// ---------------- Pass A: block-local counting sort into p-buckets ----------------
// LDS budget: 2KB pack + 2x2KB u16 scan + 600B nt + 32KB keys = 38.6KB -> 4 blocks/CU.
__global__ __launch_bounds__(512, 8) void partition_kernel(
    const int* __restrict__ predseg, const int* __restrict__ targetseg,
    unsigned short* __restrict__ keys, unsigned* __restrict__ dir,
    unsigned* __restrict__ g_nt) {
    __shared__ unsigned s_pack[NBUK / 2];       // packed u16 pair: counts, then run offsets
    __shared__ unsigned short s_sa[NBUK];       // scan ping
    __shared__ unsigned short s_sb[NBUK];       // scan pong
    __shared__ unsigned s_nt[N_CLS];
    __shared__ unsigned short s_keys[STRIPE];   // 32KB

    int tid = threadIdx.x;
    int blk = blockIdx.x;
    size_t base = (size_t)blk * STRIPE;
    int tbase = (int)(base >> PIX_SHIFT) * N_CLS;   // image uniform per stripe

    for (int i = tid; i < NBUK / 2; i += 512) s_pack[i] = 0u;
    for (int i = tid; i < N_CLS;   i += 512) s_nt[i] = 0u;
    __syncthreads();

    const int4* pv4 = (const int4*)(predseg   + base);
    const int4* cv4 = (const int4*)(targetseg + base);

    // phase 1: bucket counts (packed u16 pairs) + per-image class histogram
    for (int i = tid; i < STRIPE / 4; i += 512) {
        int4 pv = pv4[i]; int4 cv = cv4[i];
        int b0 = pv.x >> 3, b1 = pv.y >> 3, b2 = pv.z >> 3, b3 = pv.w >> 3;
        atomicAdd(&s_pack[b0 >> 1], (b0 & 1) ? 0x10000u : 1u);
        atomicAdd(&s_pack[b1 >> 1], (b1 & 1) ? 0x10000u : 1u);
        atomicAdd(&s_pack[b2 >> 1], (b2 & 1) ? 0x10000u : 1u);
        atomicAdd(&s_pack[b3 >> 1], (b3 & 1) ? 0x10000u : 1u);
        atomicAdd(&s_nt[cv.x], 1u); atomicAdd(&s_nt[cv.y], 1u);
        atomicAdd(&s_nt[cv.z], 1u); atomicAdd(&s_nt[cv.w], 1u);
    }
    __syncthreads();

    // flush n_t (150 atomics per block)
    for (int i = tid; i < N_CLS; i += 512) {
        unsigned v = s_nt[i];
        if (v) atomicAdd(&g_nt[tbase + i], v);
    }

    // unpack counts -> u16 scan array (inclusive max 16384 fits u16)
    for (int i = tid; i < NBUK; i += 512) {
        unsigned w = s_pack[i >> 1];
        s_sa[i] = (unsigned short)((w >> ((i & 1) * 16)) & 0xFFFFu);
    }
    __syncthreads();

    // Hillis-Steele inclusive scan over 1024 u16 (10 rounds, ends in s_sa)
    unsigned short* src = s_sa;
    unsigned short* dst = s_sb;
    for (int d = 1; d < NBUK; d <<= 1) {
        for (int i = tid; i < NBUK; i += 512)
            dst[i] = (unsigned short)(src[i] + (i >= d ? src[i - d] : 0));
        __syncthreads();
        unsigned short* t = src; src = dst; dst = t;
    }

    // directory (start | cnt<<15) + re-init packed run offsets
    uint2* dir2 = (uint2*)(dir + (size_t)blk * NBUK);
    for (int i = tid; i < NBUK / 2; i += 512) {
        int b0 = 2 * i;
        unsigned incl0 = src[b0], incl1 = src[b0 + 1];
        unsigned excl0 = b0 ? (unsigned)src[b0 - 1] : 0u;
        unsigned excl1 = incl0;
        uint2 de;
        de.x = excl0 | ((incl0 - excl0) << 15);
        de.y = excl1 | ((incl1 - excl1) << 15);
        dir2[i] = de;
        s_pack[i] = excl0 | (excl1 << 16);
    }
    __syncthreads();

    // phase 2: scatter keys into LDS grouped by bucket (input re-read is L2-hot)
    for (int i = tid; i < STRIPE / 4; i += 512) {
        int4 pv = pv4[i]; int4 cv = cv4[i];
        int p, b; unsigned old, slot;
        p = pv.x; b = p >> 3;
        old = atomicAdd(&s_pack[b >> 1], (b & 1) ? 0x10000u : 1u);
        slot = (old >> ((b & 1) * 16)) & 0xFFFFu;
        s_keys[slot] = (unsigned short)(((p & 7) << 12) | (tbase + cv.x));
        p = pv.y; b = p >> 3;
        old = atomicAdd(&s_pack[b >> 1], (b & 1) ? 0x10000u : 1u);
        slot = (old >> ((b & 1) * 16)) & 0xFFFFu;
        s_keys[slot] = (unsigned short)(((p & 7) << 12) | (tbase + cv.y));
        p = pv.z; b = p >> 3;
        old = atomicAdd(&s_pack[b >> 1], (b & 1) ? 0x10000u : 1u);
        slot = (old >> ((b & 1) * 16)) & 0xFFFFu;
        s_keys[slot] = (unsigned short)(((p & 7) << 12) | (tbase + cv.z));
        p = pv.w; b = p >> 3;
        old = atomicAdd(&s_pack[b >> 1], (b & 1) ? 0x10000u : 1u);
        slot = (old >> ((b & 1) * 16)) & 0xFFFFu;
        s_keys[slot] = (unsigned short)(((p & 7) << 12) | (tbase + cv.w));
    }
    __syncthreads();

    // phase 3: fully-coalesced 32KB store
    uint4* dstv = (uint4*)(keys + base);
    const uint4* srcv = (const uint4*)s_keys;
    for (int i = tid; i < (STRIPE * 2) / 16; i += 512) dstv[i] = srcv[i];
}

// ---------------- Pass B: per-bucket LDS histogram + sweep -> out[p][cls] ----------------
// LDS: 8*2400 u16-packed = 38.4KB -> 4 blocks/CU at 512 threads.
__global__ __launch_bounds__(512, 8) void hist_sweep_kernel(
    const unsigned short* __restrict__ keys, const unsigned* __restrict__ dir,
    const unsigned* __restrict__ g_nt, float* __restrict__ outb) {
    __shared__ unsigned s_hist[P_PER_BUK * T_DIM / 2];   // 9600 words
    __shared__ float s_np[P_PER_BUK];

    int tid = threadIdx.x;
    int q   = blockIdx.x;
    for (int i = tid; i < P_PER_BUK * T_DIM / 2; i += 512) s_hist[i] = 0u;
    __syncthreads();

    // 2 stripe-segments per thread; keys contiguous per segment
    for (int s = tid; s < NBLK_A; s += 512) {
        unsigned d = dir[(size_t)s * NBUK + q];
        int start = (int)(d & 0x7FFFu);
        int cnt   = (int)(d >> 15);
        const unsigned short* kp = keys + (size_t)s * STRIPE + start;
        for (int j = 0; j < cnt; ++j) {
            unsigned k = kp[j];
            unsigned bin = (k >> 12) * T_DIM + (k & 4095u);
            atomicAdd(&s_hist[bin >> 1], (bin & 1u) ? 0x10000u : 1u);
        }
    }
    __syncthreads();

    // n_p[lp] = row sums (8 rows, one wave each; rows start word-aligned)
    int wid = tid >> 6, lane = tid & 63;
    {
        unsigned sum = 0;
        const unsigned* row = s_hist + wid * (T_DIM / 2);
        for (int t = lane; t < T_DIM / 2; t += 64) {
            unsigned w = row[t];
            sum += (w & 0xFFFFu) + (w >> 16);
        }
        #pragma unroll
        for (int off = 32; off; off >>= 1) sum += __shfl_xor(sum, off);
        if (lane == 0) s_np[wid] = (float)sum;
    }
    __syncthreads();

    // sweep: each (p,cls) owned by exactly this block -> plain store
    for (int idx = tid; idx < P_PER_BUK * N_CLS; idx += 512) {
        int lp  = idx / N_CLS;
        int cls = idx - lp * N_CLS;
        float np = s_np[lp];
        float acc = 0.f;
        #pragma unroll
        for (int b = 0; b < N_BATCH; ++b) {
            int t = b * N_CLS + cls;
            unsigned bin = (unsigned)(lp * T_DIM + t);
            unsigned c = (s_hist[bin >> 1] >> ((bin & 1u) * 16)) & 0xFFFFu;
            if (c) {
                float f = (float)c;
                acc += f / (np + (float)g_nt[t] - f);
            }
        }
        outb[(size_t)(q * P_PER_BUK + lp) * N_CLS + cls] = acc;
    }
}

// ---------------- Pass C: per-row focal CE, mean ----------------
__global__ __launch_bounds__(256) void loss_kernel(
    const float* __restrict__ pred, const float* __restrict__ outbuf,
    float* __restrict__ loss_out, float cnorm) {
    __shared__ float s_l[4];
    int row  = blockIdx.x * 4 + (threadIdx.x >> 6);
    int lane = threadIdx.x & 63;
    const float* pr   = pred   + (size_t)row * N_CLS;
    const float* orow = outbuf + (size_t)row * N_CLS;

    float pv[3], ov[3];
    float rowsum = 0.f, pmax = -INFINITY;
    #pragma unroll
    for (int k = 0; k < 3; ++k) {
        int c = lane + k * 64;
        bool ok = c < N_CLS;
        pv[k] = ok ? pr[c]   : -INFINITY;
        ov[k] = ok ? orow[c] : 0.f;
        rowsum += ov[k];
        pmax = fmaxf(pmax, pv[k]);
    }
    #pragma unroll
    for (int off = 32; off; off >>= 1) {
        rowsum += __shfl_xor(rowsum, off);
        pmax = fmaxf(pmax, __shfl_xor(pmax, off));
    }
    float sumexp = 0.f;
    #pragma unroll
    for (int k = 0; k < 3; ++k) {
        int c = lane + k * 64;
        if (c < N_CLS) sumexp += __expf(pv[k] - pmax);
    }
    #pragma unroll
    for (int off = 32; off; off >>= 1) sumexp += __shfl_xor(sumexp, off);
    float lse = __logf(sumexp) + pmax;      // logp[c] = pred[c] - lse

    float inv = 1.f / rowsum;
    float ce = 0.f, bestv = -INFINITY;
    int besti = 0;
    #pragma unroll
    for (int k = 0; k < 3; ++k) {
        int c = lane + k * 64;
        if (c >= N_CLS) continue;
        float tg = ov[k] * inv;
        if (c != 0) ce -= tg * (pv[k] - lse);   // cls_w[0] = 0
        if (tg > bestv) { bestv = tg; besti = c; }  // first max within lane
    }
    #pragma unroll
    for (int off = 32; off; off >>= 1) {
        ce += __shfl_xor(ce, off);
        float bv = __shfl_xor(bestv, off);
        int   bi = __shfl_xor(besti, off);
        if (bv > bestv || (bv == bestv && bi < besti)) { bestv = bv; besti = bi; }
    }
    if (lane == 0) {
        float ptv = __expf(pr[besti] - lse);    // softmax at argmax(target)
        float x  = 1.f - ptv;
        float x2 = x * x;
        s_l[threadIdx.x >> 6] = x2 * x2 * ce * cnorm;
    }
    __syncthreads();
    if (threadIdx.x == 0) {
        float s = s_l[0] + s_l[1] + s_l[2] + s_l[3];
        atomicAdd(loss_out, s * (1.0f / (float)N_PRED));
    }
}

// Host-side: reproduce _norm_factor(4.0) — trapezoid of (1-t^5)/(1-t), 1000 pts.
static float compute_cnorm() {
    const double eps = 1e-7, gamma = 4.0;
    double h = 0.0, prev_t = 0.0, prev_y = 1.0;   // y(0) = 1
    for (int i = 1; i < 1000; ++i) {
        double t = (double)i * (1.0 - eps) / 999.0;
        double y = (1.0 - pow(t, gamma + 1.0)) / (1.0 - t);
        h += 0.5 * (y + prev_y) * (t - prev_t);
        prev_t = t; prev_y = y;
    }
    return (float)((gamma + 1.0) / h);
}

extern "C" void kernel_launch(void* const* d_in, const int* in_sizes, int n_in,
                              void* d_out, int out_size, void* d_ws, size_t ws_size,
                              hipStream_t stream) {
    const float* pred      = (const float*)d_in[0];
    const int*   predseg   = (const int*)d_in[1];
    const int*   targetseg = (const int*)d_in[2];

    unsigned char* ws = (unsigned char*)d_ws;
    unsigned short* keys = (unsigned short*)ws;
    unsigned* dir  = (unsigned*)(ws + KEYS_BYTES);
    unsigned* g_nt = (unsigned*)(ws + KEYS_BYTES + DIR_BYTES);
    float*    outb = (float*)  (ws + KEYS_BYTES + DIR_BYTES + NT_BYTES);

    float cnorm = compute_cnorm();

    hipMemsetAsync(g_nt, 0, NT_BYTES, stream);
    hipMemsetAsync(d_out, 0, sizeof(float) * (size_t)out_size, stream);

    partition_kernel <<<NBLK_A, 512, 0, stream>>>(predseg, targetseg, keys, dir, g_nt);
    hist_sweep_kernel<<<NBUK,   512, 0, stream>>>(keys, dir, g_nt, outb);
    loss_kernel      <<<N_PRED / 4, 256, 0, stream>>>(pred, outb, (float*)d_out, cnorm);
}